// Round 6
// baseline (1010.137 us; speedup 1.0000x reference)
//
#include <hip/hip_runtime.h>
#include <cstdint>
#include <cstddef>

#define NLAYERS 24
#define BATCH   4096
#define FEAT    1024

typedef _Float16 half_t;
typedef half_t half8 __attribute__((ext_vector_type(8)));
typedef float  f32x4 __attribute__((ext_vector_type(4)));

// ---------------------------------------------------------------------------
// async global -> LDS, 16B per lane. LDS dest = wave-uniform base + lane*16.
// Global source address is PER-LANE -> we order lanes' sources in fragment
// order so the linear LDS image is exactly the MFMA read order (m173 pattern).
// ---------------------------------------------------------------------------
__device__ __forceinline__ void gload_lds16(const void* g, void* l) {
    __builtin_amdgcn_global_load_lds(
        (__attribute__((address_space(1))) void*)(void*)g,
        (__attribute__((address_space(3))) void*)l,
        16, 0, 0);
}

// ---------------------------------------------------------------------------
// prep_weights: WmT[l][n][k] = (half)(W[l][k][n] * M[l][k][n])   (unchanged)
// ---------------------------------------------------------------------------
__global__ __launch_bounds__(256) void prep_weights(
    const float* __restrict__ W, const float* __restrict__ M,
    half_t* __restrict__ WmT)
{
    __shared__ float tile[64][65];

    const int bid = blockIdx.x;
    const int l   = bid >> 8;
    const int t   = bid & 255;
    const int k0  = (t >> 4) * 64;
    const int n0  = (t & 15) * 64;
    const size_t lbase = (size_t)l * 1025 * 1024;

    const int tid = threadIdx.x;
    const int rr  = tid >> 4;
    const int c4  = (tid & 15) * 4;

#pragma unroll
    for (int i = 0; i < 4; ++i) {
        const int row = rr + i * 16;
        const size_t g = lbase + (size_t)(k0 + row) * 1024 + (n0 + c4);
        const float4 w4 = *(const float4*)(W + g);
        const float4 m4 = *(const float4*)(M + g);
        tile[row][c4 + 0] = w4.x * m4.x;
        tile[row][c4 + 1] = w4.y * m4.y;
        tile[row][c4 + 2] = w4.z * m4.z;
        tile[row][c4 + 3] = w4.w * m4.w;
    }
    __syncthreads();

    const int n   = tid >> 2;
    const int k16 = (tid & 3) * 16;
    half8 lo, hi;
#pragma unroll
    for (int j = 0; j < 8; ++j) {
        lo[j] = (half_t)tile[k16 + j][n];
        hi[j] = (half_t)tile[k16 + 8 + j][n];
    }
    const size_t o = (size_t)l * 1024 * 1024 + (size_t)(n0 + n) * 1024 + (k0 + k16);
    *(half8*)(WmT + o)     = lo;
    *(half8*)(WmT + o + 8) = hi;
}

// ---------------------------------------------------------------------------
__global__ __launch_bounds__(256) void prep_bias(
    const float* __restrict__ W, float* __restrict__ bias)
{
    const int i = blockIdx.x * 256 + threadIdx.x;
    const int l = i >> 10;
    const int n = i & 1023;
    bias[i] = W[(size_t)l * 1025 * 1024 + (size_t)1024 * 1024 + n];
}

// ---------------------------------------------------------------------------
__global__ __launch_bounds__(256) void prep_xcast(
    const float* __restrict__ x, half_t* __restrict__ a0)
{
    const size_t i = ((size_t)blockIdx.x * 256 + threadIdx.x) * 8;
    const float4 u = *(const float4*)(x + i);
    const float4 v = *(const float4*)(x + i + 4);
    half8 h;
    h[0] = (half_t)u.x; h[1] = (half_t)u.y; h[2] = (half_t)u.z; h[3] = (half_t)u.w;
    h[4] = (half_t)v.x; h[5] = (half_t)v.y; h[6] = (half_t)v.z; h[7] = (half_t)v.w;
    *(half8*)(a0 + i) = h;
}

// ---------------------------------------------------------------------------
// gemm_layer v2: C[4096][1024] = relu(A @ Wm^T + bias)
// BM=128 BN=128 BK=64, 256 threads (4 waves 2x2, per-wave 64x64, acc 4x4),
// grid 256 (1 block/CU). Fragment-ordered LDS: tile stored as 16 subtiles of
// [16 rows x 32 k]; chunk c in subtile holds (r=c&15, q=c>>4) -> A[r][q*8..+7].
// ds_read_b128 by lane l = q*16+r reads chunk (subtile*64 + l): stride-1,
// conflict-free. Double-buffered prefetch, 1 barrier / K-step.
// ---------------------------------------------------------------------------
template <int LAST>
__global__ __launch_bounds__(256) void gemm_layer(
    const half_t* __restrict__ A,
    const half_t* __restrict__ Bt,
    const float*  __restrict__ bias,
    half_t* __restrict__ Ch,
    float*  __restrict__ Cf)
{
    // 16 subtiles x 512 halfs = 8192 halfs = 16 KB each; dbuf A+B = 64 KB
    __shared__ half_t As[2][8192];
    __shared__ half_t Bs[2][8192];

    const int tid  = threadIdx.x;
    const int bid  = blockIdx.x;
    const int bm   = bid >> 3;        // 0..31 (M tiles of 128)
    const int bn   = bid & 7;         // 0..7  (N tiles of 128)
    const int lane = tid & 63;
    const int q    = lane >> 4;       // 0..3
    const int r    = lane & 15;       // 0..15
    const int w    = tid >> 6;        // 0..3
    const int wr   = w >> 1;          // wave row 0..1 (64 rows)
    const int wc   = w & 1;           // wave col 0..1 (64 cols)

    const half_t* Ab = A  + (size_t)bm * 128 * 1024;
    const half_t* Bb = Bt + (size_t)bn * 128 * 1024;

    // staging: chunk = rd*256 + tid; decode to (rb, kb, r, q) fragment order.
    // A and B share the identical mapping (both [128 rows][1024 k] global).
    const int sc_r  = tid & 15;
    const int sc_q8 = ((tid >> 4) & 3) * 8;

    f32x4 acc[4][4];
#pragma unroll
    for (int m = 0; m < 4; ++m)
#pragma unroll
        for (int n = 0; n < 4; ++n)
            acc[m][n] = (f32x4){0.f, 0.f, 0.f, 0.f};

#define STAGE(ABUF, BBUF, K0)                                                   \
    {                                                                           \
        _Pragma("unroll")                                                       \
        for (int rd = 0; rd < 4; ++rd) {                                        \
            const int chunk = rd * 256 + tid;                                   \
            const int kb    = (chunk >> 6) & 1;                                 \
            const int rb    = chunk >> 7;                                       \
            const int row   = rb * 16 + sc_r;                                   \
            const int kc    = (K0) + kb * 32 + sc_q8;                           \
            const int base  = (rd * 256 + (tid & 192)) * 8;                     \
            gload_lds16(Ab + (size_t)row * 1024 + kc, (ABUF) + base);           \
            gload_lds16(Bb + (size_t)row * 1024 + kc, (BBUF) + base);           \
        }                                                                       \
    }

    // prologue: fill buffer 0
    STAGE(As[0], Bs[0], 0)

    const int lane8 = lane * 8;
    int cur = 0;

    for (int kt = 0; kt < 16; ++kt) {
        __syncthreads();   // drains vmcnt(0): buf[cur] staged; prior reads of buf[cur^1] done
        if (kt < 15) {
            half_t* An = As[cur ^ 1];
            half_t* Bn = Bs[cur ^ 1];
            const int k0n = (kt + 1) * 64;
            STAGE(An, Bn, k0n)
        }

        const half_t* Ac = As[cur];
        const half_t* Bc = Bs[cur];

        half8 a0[4], a1[4], b0[4], b1[4];
#pragma unroll
        for (int m = 0; m < 4; ++m) {
            const int sb = (wr * 4 + m) * 2;
            a0[m] = *(const half8*)(Ac + (sb + 0) * 512 + lane8);
            a1[m] = *(const half8*)(Ac + (sb + 1) * 512 + lane8);
        }
#pragma unroll
        for (int n = 0; n < 4; ++n) {
            const int sb = (wc * 4 + n) * 2;
            b0[n] = *(const half8*)(Bc + (sb + 0) * 512 + lane8);
            b1[n] = *(const half8*)(Bc + (sb + 1) * 512 + lane8);
        }
#pragma unroll
        for (int m = 0; m < 4; ++m)
#pragma unroll
            for (int n = 0; n < 4; ++n)
                acc[m][n] = __builtin_amdgcn_mfma_f32_16x16x32_f16(a0[m], b0[n], acc[m][n], 0, 0, 0);
#pragma unroll
        for (int m = 0; m < 4; ++m)
#pragma unroll
            for (int n = 0; n < 4; ++n)
                acc[m][n] = __builtin_amdgcn_mfma_f32_16x16x32_f16(a1[m], b1[n], acc[m][n], 0, 0, 0);

        cur ^= 1;
    }
#undef STAGE

    // epilogue: bias + relu, store. C/D: col = lane&15, row = (lane>>4)*4 + t
    const int colb = bn * 128 + wc * 64 + r;
    const int rowb = bm * 128 + wr * 64 + q * 4;
#pragma unroll
    for (int n = 0; n < 4; ++n) {
        const int col = colb + n * 16;
        const float bv = bias[col];
#pragma unroll
        for (int m = 0; m < 4; ++m) {
            const int row = rowb + m * 16;
#pragma unroll
            for (int t = 0; t < 4; ++t) {
                float v = acc[m][n][t] + bv;
                v = v > 0.f ? v : 0.f;
                if (LAST) Cf[(size_t)(row + t) * 1024 + col] = v;
                else      Ch[(size_t)(row + t) * 1024 + col] = (half_t)v;
            }
        }
    }
}

// ---------------------------------------------------------------------------
extern "C" void kernel_launch(void* const* d_in, const int* in_sizes, int n_in,
                              void* d_out, int out_size, void* d_ws, size_t ws_size,
                              hipStream_t stream)
{
    const float* x = (const float*)d_in[0];
    const float* W = (const float*)d_in[1];
    const float* M = (const float*)d_in[2];
    float* out = (float*)d_out;

    half_t* WmT  = (half_t*)d_ws;                                  // 24*1024*1024 fp16
    float*  bias = (float*)(WmT + (size_t)NLAYERS * 1024 * 1024);  // 24*1024 fp32
    half_t* act0 = (half_t*)(bias + NLAYERS * 1024);               // 4096*1024 fp16
    half_t* act1 = act0 + (size_t)BATCH * FEAT;                    // 4096*1024 fp16

    prep_weights<<<dim3(NLAYERS * 256), dim3(256), 0, stream>>>(W, M, WmT);
    prep_bias   <<<dim3(96),            dim3(256), 0, stream>>>(W, bias);
    prep_xcast  <<<dim3(2048),          dim3(256), 0, stream>>>(x, act0);

    half_t* cur = act0;
    half_t* nxt = act1;
    for (int l = 0; l < NLAYERS; ++l) {
        const half_t* Wl = WmT + (size_t)l * 1024 * 1024;
        const float*  bl = bias + l * 1024;
        if (l == NLAYERS - 1) {
            gemm_layer<1><<<dim3(256), dim3(256), 0, stream>>>(cur, Wl, bl, (half_t*)nullptr, out);
        } else {
            gemm_layer<0><<<dim3(256), dim3(256), 0, stream>>>(cur, Wl, bl, nxt, (float*)nullptr);
        }
        half_t* tmp = cur; cur = nxt; nxt = tmp;
    }
}

// Round 9
// 889.011 us; speedup vs baseline: 1.1362x; 1.1362x over previous
//
#include <hip/hip_runtime.h>
#include <cstdint>
#include <cstddef>

#define NLAYERS 24
#define BATCH   4096
#define FEAT    1024

typedef _Float16 half_t;
typedef half_t half8 __attribute__((ext_vector_type(8)));
typedef float  f32x4 __attribute__((ext_vector_type(4)));

// ---------------------------------------------------------------------------
// async global -> LDS, 16B per lane. LDS dest = wave-uniform base + lane*16;
// global source is per-lane, so lanes' sources are ordered in FRAGMENT order
// and the linear LDS image is exactly the MFMA read order (m173 pattern).
// ---------------------------------------------------------------------------
__device__ __forceinline__ void gload_lds16(const void* g, void* l) {
    __builtin_amdgcn_global_load_lds(
        (__attribute__((address_space(1))) void*)(void*)g,
        (__attribute__((address_space(3))) void*)l,
        16, 0, 0);
}

// ---------------------------------------------------------------------------
// prep_weights: WmT[l][n][k] = (half)(W[l][k][n] * M[l][k][n])  (unchanged)
// ---------------------------------------------------------------------------
__global__ __launch_bounds__(256) void prep_weights(
    const float* __restrict__ W, const float* __restrict__ M,
    half_t* __restrict__ WmT)
{
    __shared__ float tile[64][65];

    const int bid = blockIdx.x;
    const int l   = bid >> 8;
    const int t   = bid & 255;
    const int k0  = (t >> 4) * 64;
    const int n0  = (t & 15) * 64;
    const size_t lbase = (size_t)l * 1025 * 1024;

    const int tid = threadIdx.x;
    const int rr  = tid >> 4;
    const int c4  = (tid & 15) * 4;

#pragma unroll
    for (int i = 0; i < 4; ++i) {
        const int row = rr + i * 16;
        const size_t g = lbase + (size_t)(k0 + row) * 1024 + (n0 + c4);
        const float4 w4 = *(const float4*)(W + g);
        const float4 m4 = *(const float4*)(M + g);
        tile[row][c4 + 0] = w4.x * m4.x;
        tile[row][c4 + 1] = w4.y * m4.y;
        tile[row][c4 + 2] = w4.z * m4.z;
        tile[row][c4 + 3] = w4.w * m4.w;
    }
    __syncthreads();

    const int n   = tid >> 2;
    const int k16 = (tid & 3) * 16;
    half8 lo, hi;
#pragma unroll
    for (int j = 0; j < 8; ++j) {
        lo[j] = (half_t)tile[k16 + j][n];
        hi[j] = (half_t)tile[k16 + 8 + j][n];
    }
    const size_t o = (size_t)l * 1024 * 1024 + (size_t)(n0 + n) * 1024 + (k0 + k16);
    *(half8*)(WmT + o)     = lo;
    *(half8*)(WmT + o + 8) = hi;
}

// ---------------------------------------------------------------------------
__global__ __launch_bounds__(256) void prep_bias(
    const float* __restrict__ W, float* __restrict__ bias)
{
    const int i = blockIdx.x * 256 + threadIdx.x;
    const int l = i >> 10;
    const int n = i & 1023;
    bias[i] = W[(size_t)l * 1025 * 1024 + (size_t)1024 * 1024 + n];
}

// ---------------------------------------------------------------------------
__global__ __launch_bounds__(256) void prep_xcast(
    const float* __restrict__ x, half_t* __restrict__ a0)
{
    const size_t i = ((size_t)blockIdx.x * 256 + threadIdx.x) * 8;
    const float4 u = *(const float4*)(x + i);
    const float4 v = *(const float4*)(x + i + 4);
    half8 h;
    h[0] = (half_t)u.x; h[1] = (half_t)u.y; h[2] = (half_t)u.z; h[3] = (half_t)u.w;
    h[4] = (half_t)v.x; h[5] = (half_t)v.y; h[6] = (half_t)v.z; h[7] = (half_t)v.w;
    *(half8*)(a0 + i) = h;
}

// ---------------------------------------------------------------------------
// gemm_layer v3: C[4096][1024] = relu(A @ Wm^T + bias)
// BM=128 BN=64 BK=64, grid 512 (2 blocks/CU, 8 waves/CU), 256 threads
// (4 waves 2x2, wave tile 64x32, acc 4x2). Fragment-ordered LDS:
// subtile s = rb*2+kb holds rows rb*16..+15, k-half kb*32..+31, stored as
// 64 chunks in lane order (r=lane&15, q=lane>>4 -> 8 halfs at k=q*8).
// ds_read_b128 at s*512 + lane*8: stride-1, conflict-free.
// Double-buffered prefetch, 1 barrier per K-step.
// ---------------------------------------------------------------------------
template <int LAST>
__global__ __launch_bounds__(256, 2) void gemm_layer(
    const half_t* __restrict__ A,
    const half_t* __restrict__ Bt,
    const float*  __restrict__ bias,
    half_t* __restrict__ Ch,
    float*  __restrict__ Cf)
{
    __shared__ half_t As[2][8192];   // 128 rows x 64 k : 16 KB x2
    __shared__ half_t Bs[2][4096];   //  64 rows x 64 k :  8 KB x2  -> 48 KB

    const int tid  = threadIdx.x;
    const int bid  = blockIdx.x;
    const int bm   = bid >> 4;        // 0..31 (M tiles of 128)
    const int bn   = bid & 15;        // 0..15 (N tiles of 64); same-bn -> same XCD
    const int lane = tid & 63;
    const int q    = lane >> 4;       // 0..3
    const int r    = lane & 15;       // 0..15
    const int w    = tid >> 6;        // 0..3
    const int wr   = w >> 1;          // wave row 0..1 (64 rows)
    const int wc   = w & 1;           // wave col 0..1 (32 cols)

    const half_t* Ab = A  + (size_t)bm * 128 * 1024;
    const half_t* Bb = Bt + (size_t)bn * 64 * 1024;

    // staging decode (chunk = rd*256 + tid; lane bits give r, q)
    const int sc_r  = tid & 15;
    const int sc_q8 = ((tid >> 4) & 3) * 8;
    const int wv    = tid >> 6;

    f32x4 acc[4][2];
#pragma unroll
    for (int m = 0; m < 4; ++m)
#pragma unroll
        for (int n = 0; n < 2; ++n)
            acc[m][n] = (f32x4){0.f, 0.f, 0.f, 0.f};

    // A: 4 rounds (1024 chunks), B: 2 rounds (512 chunks)
#define STAGE(ABUF, BBUF, K0)                                                   \
    {                                                                           \
        _Pragma("unroll")                                                       \
        for (int rd = 0; rd < 4; ++rd) {                                        \
            const int s   = rd * 4 + wv;          /* subtile 0..15 */           \
            const int rb  = s >> 1;                                             \
            const int kb  = s & 1;                                              \
            const int row = rb * 16 + sc_r;                                     \
            const int kc  = (K0) + kb * 32 + sc_q8;                             \
            gload_lds16(Ab + (size_t)row * 1024 + kc,                           \
                        (ABUF) + (rd * 256 + (tid & 192)) * 8);                 \
        }                                                                       \
        _Pragma("unroll")                                                       \
        for (int rd = 0; rd < 2; ++rd) {                                        \
            const int s   = rd * 4 + wv;          /* subtile 0..7 */            \
            const int rb  = s >> 1;                                             \
            const int kb  = s & 1;                                              \
            const int row = rb * 16 + sc_r;                                     \
            const int kc  = (K0) + kb * 32 + sc_q8;                             \
            gload_lds16(Bb + (size_t)row * 1024 + kc,                           \
                        (BBUF) + (rd * 256 + (tid & 192)) * 8);                 \
        }                                                                       \
    }

    STAGE(As[0], Bs[0], 0)   // prologue

    const int lane8 = lane * 8;
    int cur = 0;

    for (int kt = 0; kt < 16; ++kt) {
        __syncthreads();   // drains vmcnt(0)+lgkmcnt(0): buf[cur] staged,
                           // prior reads of buf[cur^1] complete
        if (kt < 15) {
            STAGE(As[cur ^ 1], Bs[cur ^ 1], (kt + 1) * 64)
        }

        const half_t* Ac = As[cur];
        const half_t* Bc = Bs[cur];

        half8 a[2][4], b[2][2];
#pragma unroll
        for (int kb = 0; kb < 2; ++kb) {
#pragma unroll
            for (int m = 0; m < 4; ++m)
                a[kb][m] = *(const half8*)(Ac + ((wr * 4 + m) * 2 + kb) * 512 + lane8);
#pragma unroll
            for (int n = 0; n < 2; ++n)
                b[kb][n] = *(const half8*)(Bc + ((wc * 2 + n) * 2 + kb) * 512 + lane8);
        }
#pragma unroll
        for (int kb = 0; kb < 2; ++kb)
#pragma unroll
            for (int m = 0; m < 4; ++m)
#pragma unroll
                for (int n = 0; n < 2; ++n)
                    acc[m][n] = __builtin_amdgcn_mfma_f32_16x16x32_f16(
                        a[kb][m], b[kb][n], acc[m][n], 0, 0, 0);

        cur ^= 1;
    }
#undef STAGE

    // epilogue: bias + relu. C/D: col = lane&15, row = (lane>>4)*4 + t
    const int colb = bn * 64 + wc * 32 + r;
    const int rowb = bm * 128 + wr * 64 + q * 4;
#pragma unroll
    for (int n = 0; n < 2; ++n) {
        const int col = colb + n * 16;
        const float bv = bias[col];
#pragma unroll
        for (int m = 0; m < 4; ++m) {
            const int row = rowb + m * 16;
#pragma unroll
            for (int t = 0; t < 4; ++t) {
                float v = acc[m][n][t] + bv;
                v = v > 0.f ? v : 0.f;
                if (LAST) Cf[(size_t)(row + t) * 1024 + col] = v;
                else      Ch[(size_t)(row + t) * 1024 + col] = (half_t)v;
            }
        }
    }
}

// ---------------------------------------------------------------------------
extern "C" void kernel_launch(void* const* d_in, const int* in_sizes, int n_in,
                              void* d_out, int out_size, void* d_ws, size_t ws_size,
                              hipStream_t stream)
{
    const float* x = (const float*)d_in[0];
    const float* W = (const float*)d_in[1];
    const float* M = (const float*)d_in[2];
    float* out = (float*)d_out;

    half_t* WmT  = (half_t*)d_ws;                                  // 24*1024*1024 fp16
    float*  bias = (float*)(WmT + (size_t)NLAYERS * 1024 * 1024);  // 24*1024 fp32
    half_t* act0 = (half_t*)(bias + NLAYERS * 1024);               // 4096*1024 fp16
    half_t* act1 = act0 + (size_t)BATCH * FEAT;                    // 4096*1024 fp16

    prep_weights<<<dim3(NLAYERS * 256), dim3(256), 0, stream>>>(W, M, WmT);
    prep_bias   <<<dim3(96),            dim3(256), 0, stream>>>(W, bias);
    prep_xcast  <<<dim3(2048),          dim3(256), 0, stream>>>(x, act0);

    half_t* cur = act0;
    half_t* nxt = act1;
    for (int l = 0; l < NLAYERS; ++l) {
        const half_t* Wl = WmT + (size_t)l * 1024 * 1024;
        const float*  bl = bias + l * 1024;
        if (l == NLAYERS - 1) {
            gemm_layer<1><<<dim3(512), dim3(256), 0, stream>>>(cur, Wl, bl, (half_t*)nullptr, out);
        } else {
            gemm_layer<0><<<dim3(512), dim3(256), 0, stream>>>(cur, Wl, bl, nxt, (float*)nullptr);
        }
        half_t* tmp = cur; cur = nxt; nxt = tmp;
    }
}

// Round 10
// 840.834 us; speedup vs baseline: 1.2014x; 1.0573x over previous
//
#include <hip/hip_runtime.h>
#include <cstdint>
#include <cstddef>

#define NLAYERS 24
#define BATCH   4096
#define FEAT    1024

typedef _Float16 half_t;
typedef half_t half8 __attribute__((ext_vector_type(8)));
typedef float  f32x4 __attribute__((ext_vector_type(4)));

// ---------------------------------------------------------------------------
// async global -> LDS, 16B per lane. LDS dest = wave-uniform base + lane*16;
// global source is per-lane (fragment-ordered so LDS image = MFMA read order).
// ---------------------------------------------------------------------------
__device__ __forceinline__ void gload_lds16(const void* g, void* l) {
    __builtin_amdgcn_global_load_lds(
        (__attribute__((address_space(1))) void*)(void*)g,
        (__attribute__((address_space(3))) void*)l,
        16, 0, 0);
}

// ---------------------------------------------------------------------------
// prep_weights: WmT[l][n][k] = (half)(W[l][k][n] * M[l][k][n])  (unchanged)
// ---------------------------------------------------------------------------
__global__ __launch_bounds__(256) void prep_weights(
    const float* __restrict__ W, const float* __restrict__ M,
    half_t* __restrict__ WmT)
{
    __shared__ float tile[64][65];

    const int bid = blockIdx.x;
    const int l   = bid >> 8;
    const int t   = bid & 255;
    const int k0  = (t >> 4) * 64;
    const int n0  = (t & 15) * 64;
    const size_t lbase = (size_t)l * 1025 * 1024;

    const int tid = threadIdx.x;
    const int rr  = tid >> 4;
    const int c4  = (tid & 15) * 4;

#pragma unroll
    for (int i = 0; i < 4; ++i) {
        const int row = rr + i * 16;
        const size_t g = lbase + (size_t)(k0 + row) * 1024 + (n0 + c4);
        const float4 w4 = *(const float4*)(W + g);
        const float4 m4 = *(const float4*)(M + g);
        tile[row][c4 + 0] = w4.x * m4.x;
        tile[row][c4 + 1] = w4.y * m4.y;
        tile[row][c4 + 2] = w4.z * m4.z;
        tile[row][c4 + 3] = w4.w * m4.w;
    }
    __syncthreads();

    const int n   = tid >> 2;
    const int k16 = (tid & 3) * 16;
    half8 lo, hi;
#pragma unroll
    for (int j = 0; j < 8; ++j) {
        lo[j] = (half_t)tile[k16 + j][n];
        hi[j] = (half_t)tile[k16 + 8 + j][n];
    }
    const size_t o = (size_t)l * 1024 * 1024 + (size_t)(n0 + n) * 1024 + (k0 + k16);
    *(half8*)(WmT + o)     = lo;
    *(half8*)(WmT + o + 8) = hi;
}

// ---------------------------------------------------------------------------
__global__ __launch_bounds__(256) void prep_bias(
    const float* __restrict__ W, float* __restrict__ bias)
{
    const int i = blockIdx.x * 256 + threadIdx.x;
    const int l = i >> 10;
    const int n = i & 1023;
    bias[i] = W[(size_t)l * 1025 * 1024 + (size_t)1024 * 1024 + n];
}

// ---------------------------------------------------------------------------
__global__ __launch_bounds__(256) void prep_xcast(
    const float* __restrict__ x, half_t* __restrict__ a0)
{
    const size_t i = ((size_t)blockIdx.x * 256 + threadIdx.x) * 8;
    const float4 u = *(const float4*)(x + i);
    const float4 v = *(const float4*)(x + i + 4);
    half8 h;
    h[0] = (half_t)u.x; h[1] = (half_t)u.y; h[2] = (half_t)u.z; h[3] = (half_t)u.w;
    h[4] = (half_t)v.x; h[5] = (half_t)v.y; h[6] = (half_t)v.z; h[7] = (half_t)v.w;
    *(half8*)(a0 + i) = h;
}

// ---------------------------------------------------------------------------
// gemm_layer v4: BM=128 BN=64 BK=64, 512 blocks (2/CU, 8 waves/CU), 4 waves.
// 3 STATIC LDS buffers in rotation + counted vmcnt(6) before raw s_barrier:
// stage for tile k+2 issued during tile k stays in flight across the barrier
// (never vmcnt(0) in steady state). ds_read via volatile inline asm (no
// memory operand -> compiler cannot insert its own conservative vmcnt(0));
// explicit lgkmcnt(0)+sched_barrier before MFMA cluster (rule #18).
//
// Wait ledger (per wave, 6 loads per STAGE):
//   prologue: S0,S1 issued (12) -> vmcnt(6): S0 done -> barrier
//   tile k:   STAGE S_{k+2} (outstanding S_{k+1}+S_{k+2}) -> COMPUTE buf_k
//             -> vmcnt(6): S_{k+1} done -> barrier   [publishes for k+1]
//   buffer being overwritten by S_{k+2} was last read at tile k-1, and all
//   waves passed the barrier ending k-1 before any wave issues S_{k+2}.
// ---------------------------------------------------------------------------
#define DSR(dst, addr, OFF) \
    asm volatile("ds_read_b128 %0, %1 offset:" OFF : "=v"(dst) : "v"(addr))

template <int LAST>
__global__ __launch_bounds__(256, 2) void gemm_layer(
    const half_t* __restrict__ A,
    const half_t* __restrict__ Bt,
    const float*  __restrict__ bias,
    half_t* __restrict__ Ch,
    float*  __restrict__ Cf)
{
    __shared__ half_t As0[8192], As1[8192], As2[8192];   // 16 KB each
    __shared__ half_t Bs0[4096], Bs1[4096], Bs2[4096];   //  8 KB each -> 72 KB

    const int tid  = threadIdx.x;
    const int bid  = blockIdx.x;
    const int bm   = bid >> 4;        // 0..31
    const int bn   = bid & 15;        // 0..15
    const int lane = tid & 63;
    const int q    = lane >> 4;
    const int r    = lane & 15;
    const int w    = tid >> 6;
    const int wr   = w >> 1;          // 0..1
    const int wc   = w & 1;           // 0..1

    const half_t* Ab = A  + (size_t)bm * 128 * 1024;
    const half_t* Bb = Bt + (size_t)bn * 64 * 1024;

    const int sc_r  = tid & 15;
    const int sc_q8 = ((tid >> 4) & 3) * 8;
    const int wv    = tid >> 6;

    // LDS byte addresses (generic->LDS: low 32 bits are the LDS offset)
    const uint32_t As0u = (uint32_t)(uintptr_t)(void*)As0;
    const uint32_t As1u = (uint32_t)(uintptr_t)(void*)As1;
    const uint32_t As2u = (uint32_t)(uintptr_t)(void*)As2;
    const uint32_t Bs0u = (uint32_t)(uintptr_t)(void*)Bs0;
    const uint32_t Bs1u = (uint32_t)(uintptr_t)(void*)Bs1;
    const uint32_t Bs2u = (uint32_t)(uintptr_t)(void*)Bs2;
    const uint32_t aoffw = (uint32_t)(wr * 8192 + lane * 16);
    const uint32_t boffw = (uint32_t)(wc * 4096 + lane * 16);

    f32x4 acc[4][2];
#pragma unroll
    for (int m = 0; m < 4; ++m)
#pragma unroll
        for (int n = 0; n < 2; ++n)
            acc[m][n] = (f32x4){0.f, 0.f, 0.f, 0.f};

    // 6 gload_lds per wave: 4 A-rounds + 2 B-rounds, fragment order
#define STAGE6(K0, SA, SB)                                                     \
    {                                                                          \
        _Pragma("unroll")                                                      \
        for (int rd = 0; rd < 4; ++rd) {                                       \
            const int s   = rd * 4 + wv;                                       \
            const int row = (s >> 1) * 16 + sc_r;                              \
            const int kc  = (K0) + (s & 1) * 32 + sc_q8;                       \
            gload_lds16(Ab + (size_t)row * 1024 + kc,                          \
                        (SA) + (rd * 256 + (tid & 192)) * 8);                  \
        }                                                                      \
        _Pragma("unroll")                                                      \
        for (int rd = 0; rd < 2; ++rd) {                                       \
            const int s   = rd * 4 + wv;                                       \
            const int row = (s >> 1) * 16 + sc_r;                              \
            const int kc  = (K0) + (s & 1) * 32 + sc_q8;                       \
            gload_lds16(Bb + (size_t)row * 1024 + kc,                          \
                        (SB) + (rd * 256 + (tid & 192)) * 8);                  \
        }                                                                      \
    }

#define COMPUTE(RAu, RBu)                                                      \
    {                                                                          \
        half8 a[2][4], b[2][2];                                                \
        const uint32_t aA = (RAu) + aoffw;                                     \
        const uint32_t aB = (RBu) + boffw;                                     \
        DSR(a[0][0], aA, "0");    DSR(a[1][0], aA, "1024");                    \
        DSR(a[0][1], aA, "2048"); DSR(a[1][1], aA, "3072");                    \
        DSR(a[0][2], aA, "4096"); DSR(a[1][2], aA, "5120");                    \
        DSR(a[0][3], aA, "6144"); DSR(a[1][3], aA, "7168");                    \
        DSR(b[0][0], aB, "0");    DSR(b[1][0], aB, "1024");                    \
        DSR(b[0][1], aB, "2048"); DSR(b[1][1], aB, "3072");                    \
        asm volatile("s_waitcnt lgkmcnt(0)" ::: "memory");                     \
        __builtin_amdgcn_sched_barrier(0);                                     \
        _Pragma("unroll")                                                      \
        for (int kb = 0; kb < 2; ++kb)                                         \
            _Pragma("unroll")                                                  \
            for (int m = 0; m < 4; ++m)                                        \
                _Pragma("unroll")                                              \
                for (int n = 0; n < 2; ++n)                                    \
                    acc[m][n] = __builtin_amdgcn_mfma_f32_16x16x32_f16(        \
                        a[kb][m], b[kb][n], acc[m][n], 0, 0, 0);               \
        __builtin_amdgcn_sched_barrier(0);                                     \
    }

#define SYNC6() { asm volatile("s_waitcnt vmcnt(6)" ::: "memory");             \
                  __builtin_amdgcn_s_barrier();                                \
                  __builtin_amdgcn_sched_barrier(0); }
#define SYNC0() { asm volatile("s_waitcnt vmcnt(0)" ::: "memory");             \
                  __builtin_amdgcn_s_barrier();                                \
                  __builtin_amdgcn_sched_barrier(0); }

    // prologue: S_0 -> buf0, S_1 -> buf1
    STAGE6(0,  As0, Bs0)
    STAGE6(64, As1, Bs1)
    SYNC6()

    for (int t = 0; t < 5; ++t) {
        STAGE6((3 * t + 2) * 64, As2, Bs2)      // S_{3t+2} -> buf2
        COMPUTE(As0u, Bs0u)                     // tile 3t from buf0
        SYNC6()
        STAGE6((3 * t + 3) * 64, As0, Bs0)      // S_{3t+3} -> buf0
        COMPUTE(As1u, Bs1u)                     // tile 3t+1 from buf1
        SYNC6()
        if (t < 4) {
            STAGE6((3 * t + 4) * 64, As1, Bs1)  // S_{3t+4} -> buf1
            COMPUTE(As2u, Bs2u)                 // tile 3t+2 from buf2
            SYNC6()
        } else {
            COMPUTE(As2u, Bs2u)                 // tile 14 from buf2
            SYNC0()                             // drain S_15 before last tile
        }
    }
    COMPUTE(As0u, Bs0u)                         // tile 15 from buf0

#undef STAGE6
#undef COMPUTE
#undef SYNC6
#undef SYNC0

    // epilogue: bias + relu. C/D: col = lane&15, row = (lane>>4)*4 + t
    const int colb = bn * 64 + wc * 32 + r;
    const int rowb = bm * 128 + wr * 64 + q * 4;
#pragma unroll
    for (int n = 0; n < 2; ++n) {
        const int col = colb + n * 16;
        const float bv = bias[col];
#pragma unroll
        for (int m = 0; m < 4; ++m) {
            const int row = rowb + m * 16;
#pragma unroll
            for (int t = 0; t < 4; ++t) {
                float v = acc[m][n][t] + bv;
                v = v > 0.f ? v : 0.f;
                if (LAST) Cf[(size_t)(row + t) * 1024 + col] = v;
                else      Ch[(size_t)(row + t) * 1024 + col] = (half_t)v;
            }
        }
    }
}

// ---------------------------------------------------------------------------
extern "C" void kernel_launch(void* const* d_in, const int* in_sizes, int n_in,
                              void* d_out, int out_size, void* d_ws, size_t ws_size,
                              hipStream_t stream)
{
    const float* x = (const float*)d_in[0];
    const float* W = (const float*)d_in[1];
    const float* M = (const float*)d_in[2];
    float* out = (float*)d_out;

    half_t* WmT  = (half_t*)d_ws;                                  // 24*1024*1024 fp16
    float*  bias = (float*)(WmT + (size_t)NLAYERS * 1024 * 1024);  // 24*1024 fp32
    half_t* act0 = (half_t*)(bias + NLAYERS * 1024);               // 4096*1024 fp16
    half_t* act1 = act0 + (size_t)BATCH * FEAT;                    // 4096*1024 fp16

    prep_weights<<<dim3(NLAYERS * 256), dim3(256), 0, stream>>>(W, M, WmT);
    prep_bias   <<<dim3(96),            dim3(256), 0, stream>>>(W, bias);
    prep_xcast  <<<dim3(2048),          dim3(256), 0, stream>>>(x, act0);

    half_t* cur = act0;
    half_t* nxt = act1;
    for (int l = 0; l < NLAYERS; ++l) {
        const half_t* Wl = WmT + (size_t)l * 1024 * 1024;
        const float*  bl = bias + l * 1024;
        if (l == NLAYERS - 1) {
            gemm_layer<1><<<dim3(512), dim3(256), 0, stream>>>(cur, Wl, bl, (half_t*)nullptr, out);
        } else {
            gemm_layer<0><<<dim3(512), dim3(256), 0, stream>>>(cur, Wl, bl, nxt, (float*)nullptr);
        }
        half_t* tmp = cur; cur = nxt; nxt = tmp;
    }
}